// Round 7
// baseline (77.622 us; speedup 1.0000x reference)
//
#include <hip/hip_runtime.h>
#include <stdint.h>

// SpikingKWTA analytical collapse (verified R1/R2/R6, absmax 0.0):
//   potentials stay exactly 0.0f after every step => spk == bincount(ids),
//   final pot == 0 => values = spk*1e6; lax.top_k tie-break = lowest index.
//   Key (count<<32)|(0xFFFFFFFF - v): max-order == (count desc, index asc).
//   gains[v] = count ? 0.6 : 1.0; gains[top5] = 1.5. L>=1 => fallback dead.
//
// R7: ONE dispatch, 128 blocks, ZERO inter-block communication.
//   Every block redundantly builds the FULL histogram of the 4096 ids in its
//   own LDS hash (64 KB: u64 slot = count<<32 | id+1) -- redundant compute is
//   free in wall time (blocks parallel across CUs; id reads broadcast L2).
//   Each block then serves its own 1024-entry V-slice: 1.0/0.6 via lookup,
//   computes the (identical) top-5 locally, applies 1.5s inside its slice.
//   Workgroup barriers only (R2 lesson: agent-scope fences = 43us L2 flush).

typedef unsigned long long u64;

#define TB 1024
#define SLICE 1024
#define HSZ 8192
#define HMASK (HSZ - 1)
#define K_WIN 5

static __device__ __forceinline__ uint32_t hashf(uint32_t x) {
    return (x * 2654435761u) >> 19;  // top 13 bits of Knuth mix
}
static __device__ __forceinline__ u64 u64max(u64 a, u64 b) { return a > b ? a : b; }

__global__ __launch_bounds__(TB) void kwta_kernel(const int* __restrict__ ids,
                                                  float* __restrict__ gains,
                                                  int L, int V) {
    __shared__ u64 slot[HSZ];          // (count<<32) | (id+1); 0 = empty
    __shared__ u64 sWave[TB / 64];
    __shared__ u64 sWin;
    __shared__ u64 sWinners[K_WIN];

    const int tid = threadIdx.x;
    const int lane = tid & 63, wid = tid >> 6;
    const int base = blockIdx.x * SLICE;

    for (int i = tid; i < HSZ; i += TB) slot[i] = 0ull;
    __syncthreads();

    // --- Phase A: full histogram (redundant per block) ---
    for (int i0 = tid * 4; i0 < L; i0 += TB * 4) {
        int idv[4];
        int n = 0;
        if (i0 + 3 < L) {
            int4 w = *reinterpret_cast<const int4*>(ids + i0);
            idv[0] = w.x; idv[1] = w.y; idv[2] = w.z; idv[3] = w.w;
            n = 4;
        } else {
            for (; i0 + n < L && n < 4; ++n) idv[n] = ids[i0 + n];
        }
        for (int j = 0; j < n; ++j) {
            uint32_t id = (uint32_t)idv[j];
            uint32_t s = hashf(id) & HMASK;
            for (;;) {
                u64 cur = slot[s];
                uint32_t lo = (uint32_t)cur;
                if (lo == id + 1u) { atomicAdd(&slot[s], 1ull << 32); break; }
                if (lo == 0u) {  // empty (high bits can't be set while lo==0)
                    u64 got = atomicCAS(&slot[s], 0ull, (1ull << 32) | (u64)(id + 1u));
                    if (got == 0ull) break;
                    if ((uint32_t)got == id + 1u) { atomicAdd(&slot[s], 1ull << 32); break; }
                    // else: another id won this slot -> probe on
                }
                s = (s + 1) & HMASK;
            }
        }
    }
    __syncthreads();

    // --- Phase B: serve own slice (lookup count, write 1.0 / 0.6) ---
    {
        int v = base + tid;  // SLICE == TB: one entry per thread
        if (v < V) {
            uint32_t s = hashf((uint32_t)v) & HMASK;
            uint32_t c = 0u;
            for (;;) {
                u64 cur = slot[s];
                uint32_t lo = (uint32_t)cur;
                if (lo == (uint32_t)v + 1u) { c = (uint32_t)(cur >> 32); break; }
                if (lo == 0u) break;
                s = (s + 1) & HMASK;
            }
            gains[v] = c ? 0.6f : 1.0f;
        }
    }

    // --- Phase C: local top-5 over HSZ/TB = 8 slots/thread (keys unique) ---
    u64 loc[K_WIN] = {0ull, 0ull, 0ull, 0ull, 0ull};
    for (int i = tid; i < HSZ; i += TB) {
        u64 cur = slot[i];
        if (cur) {
            uint32_t id = (uint32_t)cur - 1u;
            u64 key = (cur & 0xFFFFFFFF00000000ull) | (u64)(0xFFFFFFFFu - id);
            if (key > loc[K_WIN - 1]) {
                loc[K_WIN - 1] = key;
                for (int j = K_WIN - 1; j > 0 && loc[j] > loc[j - 1]; --j) {
                    u64 t = loc[j]; loc[j] = loc[j - 1]; loc[j - 1] = t;
                }
            }
        }
    }

    // --- Phase D: block top-5 reduce (identical result in every block) ---
    int nz = 0;
    for (int it = 0; it < K_WIN; ++it) {
        u64 k = loc[0];
        for (int off = 32; off; off >>= 1) k = u64max(k, __shfl_xor(k, off));
        if (lane == 0) sWave[wid] = k;
        __syncthreads();
        if (tid == 0) {
            u64 w = sWave[0];
            for (int i = 1; i < TB / 64; ++i) w = u64max(w, sWave[i]);
            sWin = w;
            sWinners[it] = w;
        }
        __syncthreads();
        u64 w = sWin;
        if (w && loc[0] == w) {  // unique key -> exactly one holder retires it
            for (int j = 0; j < K_WIN - 1; ++j) loc[j] = loc[j + 1];
            loc[K_WIN - 1] = 0ull;
        }
        if (w) ++nz;
        __syncthreads();  // sWave/sWin reuse hazard
    }

    // --- Phase E: apply 1.5 for winners inside own slice ---
    // (after Phase B stores; barriers in Phase D drained them)
    if (tid < K_WIN && tid < nz) {
        u64 w = sWinners[tid];
        uint32_t idx = 0xFFFFFFFFu - (uint32_t)(w & 0xFFFFFFFFull);
        if ((int)idx >= base && (int)idx < base + SLICE && (int)idx < V)
            gains[idx] = 1.5f;
    }

    // --- Phase F: degenerate (<5 distinct ids) fallback -- dead for bench ---
    if (tid == 0 && nz < K_WIN) {
        // remaining picks = lowest-index zero-count entries (lax.top_k order)
        int need = K_WIN - nz;
        for (uint32_t v = 0; need > 0 && v < (uint32_t)V; ++v) {
            uint32_t s = hashf(v) & HMASK;
            uint32_t c = 0u;
            for (;;) {
                u64 cur = slot[s];
                uint32_t lo = (uint32_t)cur;
                if (lo == 0u) break;
                if (lo == v + 1u) { c = (uint32_t)(cur >> 32); break; }
                s = (s + 1) & HMASK;
            }
            if (c == 0u) {
                if ((int)v >= base && (int)v < base + SLICE) gains[v] = 1.5f;
                --need;
            }
        }
    }
}

extern "C" void kernel_launch(void* const* d_in, const int* in_sizes, int n_in,
                              void* d_out, int out_size, void* d_ws, size_t ws_size,
                              hipStream_t stream) {
    const int* ids = (const int*)d_in[0];   // token_ids (int32 per harness)
    const int L = in_sizes[0];              // 4096
    const int V = out_size;                 // 131072
    float* gains = (float*)d_out;
    const int nblk = (V + SLICE - 1) / SLICE;  // 128
    kwta_kernel<<<nblk, TB, 0, stream>>>(ids, gains, L, V);
}